// Round 1
// baseline (434.887 us; speedup 1.0000x reference)
//
#include <hip/hip_runtime.h>

#define MARGIN   0.3f
#define S_SCALE  15.0f
#define LAMDA    2.0f
#define NB       8192
#define NC       10000
#define MAXLOGIT 15.0f   // logits = 15*costh, costh in [0,1] -> fixed, safe shift

// One block per row. Single pass: partial sums of exp(15*x - 15) via float4
// loads, block-reduce, thread 0 patches in the margin-adjusted target term.
__global__ __launch_bounds__(256) void dam_row_loss(const float* __restrict__ costh,
                                                    const int* __restrict__ label,
                                                    float* __restrict__ row_loss) {
    const int row = blockIdx.x;
    const int tid = threadIdx.x;
    const float* __restrict__ rowp = costh + (size_t)row * NC;

    float s = 0.0f;
    const float4* __restrict__ rp4 = (const float4*)rowp;  // 40000 B rows: 16B aligned
    const int n4 = NC / 4;  // 2500, no tail
    for (int i = tid; i < n4; i += 256) {
        float4 v = rp4[i];
        s += __expf(fmaf(S_SCALE, v.x, -MAXLOGIT));
        s += __expf(fmaf(S_SCALE, v.y, -MAXLOGIT));
        s += __expf(fmaf(S_SCALE, v.z, -MAXLOGIT));
        s += __expf(fmaf(S_SCALE, v.w, -MAXLOGIT));
    }

    // wave64 shuffle reduce, then across the 4 waves via LDS
    #pragma unroll
    for (int off = 32; off > 0; off >>= 1)
        s += __shfl_down(s, off, 64);
    __shared__ float wsum[4];
    if ((tid & 63) == 0) wsum[tid >> 6] = s;
    __syncthreads();

    if (tid == 0) {
        float tot = wsum[0] + wsum[1] + wsum[2] + wsum[3];
        const int lbl = label[row];
        const float cos_t = rowp[lbl];
        const float delta = (MARGIN / LAMDA) * __expf(1.0f - cos_t);
        const float t_logit = S_SCALE * (cos_t - delta);           // modified target logit
        // swap original target term for the margin-adjusted one
        tot = tot - __expf(fmaf(S_SCALE, cos_t, -MAXLOGIT)) + __expf(t_logit - MAXLOGIT);
        const float lse = MAXLOGIT + __logf(tot);
        row_loss[row] = lse - t_logit;                             // -logp[target]
    }
}

// 8192 floats -> scalar mean. Single block; writes d_out unconditionally
// (d_out is re-poisoned to 0xAA before every timed launch).
__global__ __launch_bounds__(256) void dam_reduce(const float* __restrict__ row_loss,
                                                  float* __restrict__ out) {
    const int tid = threadIdx.x;
    float s = 0.0f;
    for (int i = tid; i < NB; i += 256) s += row_loss[i];
    #pragma unroll
    for (int off = 32; off > 0; off >>= 1)
        s += __shfl_down(s, off, 64);
    __shared__ float wsum[4];
    if ((tid & 63) == 0) wsum[tid >> 6] = s;
    __syncthreads();
    if (tid == 0) out[0] = (wsum[0] + wsum[1] + wsum[2] + wsum[3]) * (1.0f / (float)NB);
}

extern "C" void kernel_launch(void* const* d_in, const int* in_sizes, int n_in,
                              void* d_out, int out_size, void* d_ws, size_t ws_size,
                              hipStream_t stream) {
    const float* costh = (const float*)d_in[0];
    const int*   label = (const int*)d_in[1];
    float* out = (float*)d_out;
    float* row_loss = (float*)d_ws;  // 8192 floats = 32 KB scratch

    dam_row_loss<<<NB, 256, 0, stream>>>(costh, label, row_loss);
    dam_reduce<<<1, 256, 0, stream>>>(row_loss, out);
}